// Round 11
// baseline (114.128 us; speedup 1.0000x reference)
//
#include <hip/hip_runtime.h>
#include <math.h>

typedef __attribute__((ext_vector_type(4))) float f32x4;
typedef _Float16 f16x8 __attribute__((ext_vector_type(8)));
typedef _Float16 f16x4v __attribute__((ext_vector_type(4)));

#define S_LEN 2048
#define D_HEAD 64
#define C2 0.18033688011112043f   /* log2(e)/8 */

static __device__ __forceinline__ float exp2v(float x) { // v_exp_f32 = 2^x
    float r; asm("v_exp_f32 %0, %1" : "=v"(r) : "v"(x)); return r;
}

static __device__ __forceinline__ void gl_lds16(const void* g, void* l) {
    __builtin_amdgcn_global_load_lds(
        (const __attribute__((address_space(1))) unsigned int*)g,
        (__attribute__((address_space(3))) unsigned int*)l, 16, 0, 0);
}

// ---- prep: T5 bias baked to [h][delta+2047], pre-scaled by log2(e)/8 ----
__global__ void prep_bias(const float* __restrict__ table, float* __restrict__ bias_d) {
    int idx = blockIdx.x * blockDim.x + threadIdx.x;   // 0..4095
    if (idx >= 4096) return;
    int delta = idx - 2047;                 // k - q
    int bpos = (delta > 0) ? 16 : 0;
    int ad = delta < 0 ? -delta : delta;
    int rel;
    if (ad < 8) {
        rel = bpos + ad;
    } else {
        float rp = (float)ad;
        int lg = 8 + (int)(logf(rp / 8.0f) / 2.772588722239781f * 8.0f);  // log(16)
        if (lg > 15) lg = 15;
        rel = bpos + lg;
    }
    #pragma unroll
    for (int h = 0; h < 4; ++h)
        bias_d[h * 4096 + idx] = C2 * table[rel * 4 + h];
}

// ---- prep: elementwise fp32 -> fp16 (for K) ----
__global__ void prep_half(const float* __restrict__ src, _Float16* __restrict__ dst) {
    size_t i8 = ((size_t)blockIdx.x * 256 + threadIdx.x) * 8;
    f32x4 a = *(const f32x4*)(src + i8);
    f32x4 b = *(const f32x4*)(src + i8 + 4);
    f16x8 h;
    h[0] = (_Float16)a[0]; h[1] = (_Float16)a[1];
    h[2] = (_Float16)a[2]; h[3] = (_Float16)a[3];
    h[4] = (_Float16)b[0]; h[5] = (_Float16)b[1];
    h[6] = (_Float16)b[2]; h[7] = (_Float16)b[3];
    *(f16x8*)(dst + i8) = h;
}

// ---- prep: V [bh][k][d] fp32  ->  V^T fp16 [bh][d][k] ----
__global__ void prep_vt(const float* __restrict__ V, _Float16* __restrict__ vt) {
    __shared__ float tile[64][65];
    const int bh = blockIdx.y;
    const int k0 = blockIdx.x * 64;
    const int t = threadIdx.x;
    {
        int r = t >> 2, c0 = (t & 3) * 16;
        const float* src = V + ((size_t)bh * S_LEN + k0 + r) * D_HEAD + c0;
        #pragma unroll
        for (int i = 0; i < 16; i += 4) {
            f32x4 v = *(const f32x4*)(src + i);
            tile[r][c0 + i + 0] = v[0];
            tile[r][c0 + i + 1] = v[1];
            tile[r][c0 + i + 2] = v[2];
            tile[r][c0 + i + 3] = v[3];
        }
    }
    __syncthreads();
    {
        int d = t >> 2, kc = (t & 3) * 16;
        size_t ob = ((size_t)bh * D_HEAD + d) * S_LEN + k0 + kc;
        #pragma unroll
        for (int half = 0; half < 2; ++half) {
            f16x8 hv;
            #pragma unroll
            for (int i = 0; i < 8; ++i)
                hv[i] = (_Float16)tile[kc + half * 8 + i][d];
            *(f16x8*)(vt + ob + half * 8) = hv;
        }
    }
}

// ============================================================================
// main: two-pass fused attention, log2-domain max-free softmax, all-fp16.
// Round-11: 4 waves x 16 q-rows, each wave owns the FULL 64-k width.
//  * p flush = wave-private: lgkmcnt(0) only (NO block barrier), 4 plain
//    stores of 4 rows x 256B contiguous runs (r8/r9's proven lever, doubled,
//    without r10's sync cost).
//  * P1 row-sum: 2 shfl_xor, no LDS stats, no barrier.
//  * epilogue: direct per-wave stores, no cross-wave reduce.
//  * mask folded into bias at load: bvm=(m?b:-1e9)+lr2 -> inner loop is
//    fmaf+exp2 only.
// LDS 48.5KB: [0,32K) staging dbuf (P1: K128/iter; P2: K64+V64/iter);
// [32K,40K) Q f16 (wave-private rows); [40K,48.5K) pbuf 4 x [16][68] f16.
// 3 blocks/CU. Same math as r9 -> absmax identical.
// ============================================================================
__launch_bounds__(256, 3)
__global__ void attn_main(const float* __restrict__ Q, const int* __restrict__ mask,
                          const float* __restrict__ bias2,
                          const _Float16* __restrict__ kh_g,
                          const _Float16* __restrict__ vt_g,
                          float* __restrict__ outp, float* __restrict__ p_out) {
    __shared__ __align__(16) char smem[49664];

    const int tid = threadIdx.x;
    const int w = tid >> 6, l = tid & 63;
    const int g = l >> 4, lq = l & 15;
    const int r7 = lq & 7;
    const int bid = blockIdx.x;
    const int bh = bid & 15, b = bh >> 2, h = bh & 3;   // bid%8 == bh%8: bh pinned per XCD
    const int q0 = (bid >> 4) * 64;

    const float* Qp = Q + (size_t)bh * (S_LEN * D_HEAD);
    const int* mp = mask + b * S_LEN;
    const _Float16* khp = kh_g + (size_t)bh * (S_LEN * D_HEAD);
    const _Float16* vhp = vt_g + (size_t)bh * (S_LEN * D_HEAD);

    // ---- stage Q -> f16 (swizzled, WAVE-PRIVATE rows) at smem[32K..40K) ----
    _Float16* qarea = (_Float16*)(smem + 32768);
    {
        int sr = tid >> 2, tb = tid & 3;    // wave w writes rows 16w..16w+16
        const float* src = Qp + (size_t)(q0 + sr) * D_HEAD + tb * 16;
        f32x4 a = *(const f32x4*)src;
        f32x4 c = *(const f32x4*)(src + 4);
        f32x4 d2 = *(const f32x4*)(src + 8);
        f32x4 e = *(const f32x4*)(src + 12);
        f16x8 hv0, hv1;
        hv0[0] = (_Float16)a[0]; hv0[1] = (_Float16)a[1];
        hv0[2] = (_Float16)a[2]; hv0[3] = (_Float16)a[3];
        hv0[4] = (_Float16)c[0]; hv0[5] = (_Float16)c[1];
        hv0[6] = (_Float16)c[2]; hv0[7] = (_Float16)c[3];
        hv1[0] = (_Float16)d2[0]; hv1[1] = (_Float16)d2[1];
        hv1[2] = (_Float16)d2[2]; hv1[3] = (_Float16)d2[3];
        hv1[4] = (_Float16)e[0]; hv1[5] = (_Float16)e[1];
        hv1[6] = (_Float16)e[2]; hv1[7] = (_Float16)e[3];
        *(f16x8*)(qarea + sr * 64 + (((2 * tb + 0) ^ (sr & 7)) * 8)) = hv0;
        *(f16x8*)(qarea + sr * 64 + (((2 * tb + 1) ^ (sr & 7)) * 8)) = hv1;
    }

    // staging geometry (256 threads: 4 gl_lds issues of 4KB each per 16KB tile)
    const int rr3 = tid >> 3;                       // row-in-32-group
    const int ub0 = (((tid & 7) ^ (rr3 & 7)) * 8);  // swizzled 8-elem block
    // P1 prologue: stage K rows 0..127 -> buf0 [0,16K)
    const _Float16* s1 = khp + (size_t)rr3 * 64 + ub0;
    gl_lds16(s1, smem + tid * 16);
    gl_lds16(s1 + 2048, smem + 4096 + tid * 16);
    gl_lds16(s1 + 4096, smem + 8192 + tid * 16);
    gl_lds16(s1 + 6144, smem + 12288 + tid * 16);

    // Q frags (wave-private rows -> no barrier needed; compiler emits lgkm wait)
    f16x8 qf[2];
    const int qrow = 16 * w + lq;
    qf[0] = *(const f16x8*)(qarea + qrow * 64 + ((g ^ r7) * 8));
    qf[1] = *(const f16x8*)(qarea + qrow * 64 + (((4 + g) ^ r7) * 8));
    const int qq = q0 + qrow;

    asm volatile("s_waitcnt vmcnt(0)" ::: "memory");
    __builtin_amdgcn_s_barrier();

    // ================= PASS 1: l = sum(2^s2), K-tile 128, 16 iters =================
    const int* mP1 = mp + 4 * g;
    const float* bP1 = bias2 + h * 4096 + 2047 - qq + 4 * g;
    float lsum = 0.0f;
    for (int t = 0; t < 16; ++t) {
        const char* kb = smem + (t & 1) * 16384;
        f32x4 bvm[8];
        #pragma unroll
        for (int t2 = 0; t2 < 8; ++t2) {
            const int4 mv = *(const int4*)(mP1 + 16 * t2);
            const f32x4 bv = *(const f32x4*)(bP1 + 16 * t2);
            bvm[t2][0] = mv.x ? bv[0] : -1e9f;
            bvm[t2][1] = mv.y ? bv[1] : -1e9f;
            bvm[t2][2] = mv.z ? bv[2] : -1e9f;
            bvm[t2][3] = mv.w ? bv[3] : -1e9f;
        }
        if (t < 15) {
            s1 += 8192;
            char* nb = smem + ((t + 1) & 1) * 16384 + tid * 16;
            gl_lds16(s1, nb);
            gl_lds16(s1 + 2048, nb + 4096);
            gl_lds16(s1 + 4096, nb + 8192);
            gl_lds16(s1 + 6144, nb + 12288);
        }
        __builtin_amdgcn_sched_barrier(0);
        #pragma unroll
        for (int t2 = 0; t2 < 8; ++t2) {
            const char* base = kb + (16 * t2 + lq) * 128;
            f16x8 a0 = *(const f16x8*)(base + (g ^ r7) * 16);
            f16x8 a1 = *(const f16x8*)(base + ((4 + g) ^ r7) * 16);
            f32x4 acc = {0.f, 0.f, 0.f, 0.f};
            acc = __builtin_amdgcn_mfma_f32_16x16x32_f16(a0, qf[0], acc, 0, 0, 0);
            acc = __builtin_amdgcn_mfma_f32_16x16x32_f16(a1, qf[1], acc, 0, 0, 0);
            lsum += exp2v(fmaf(acc[0], C2, bvm[t2][0]))
                  + exp2v(fmaf(acc[1], C2, bvm[t2][1]))
                  + exp2v(fmaf(acc[2], C2, bvm[t2][2]))
                  + exp2v(fmaf(acc[3], C2, bvm[t2][3]));
        }
        mP1 += 128; bP1 += 128;
        asm volatile("s_waitcnt vmcnt(0)" ::: "memory");
        __builtin_amdgcn_sched_barrier(0);
        __builtin_amdgcn_s_barrier();
        __builtin_amdgcn_sched_barrier(0);
    }
    // full row sum: reduce across the 4 g-groups (k-slices) only
    lsum += __shfl_xor(lsum, 16);
    lsum += __shfl_xor(lsum, 32);
    float lr2q;
    { float lg; asm("v_log_f32 %0, %1" : "=v"(lg) : "v"(lsum)); lr2q = -lg; }

    // ---- P2 prologue (buf0: K64 at [0,8K), V64 at [8K,16K)) ----
    const _Float16* sKh = khp + (size_t)rr3 * 64 + ub0;
    const _Float16* sVh = vhp + (size_t)rr3 * 2048 + ub0;
    gl_lds16(sKh, smem + tid * 16);
    gl_lds16(sKh + 2048, smem + 4096 + tid * 16);
    gl_lds16(sVh, smem + 8192 + tid * 16);
    gl_lds16(sVh + 65536, smem + 12288 + tid * 16);
    asm volatile("s_waitcnt vmcnt(0)" ::: "memory");
    __builtin_amdgcn_s_barrier();

    // ================= PASS 2: p = 2^(fma+bvm2), wave-private 256B-run flush =================
    f32x4 acco[4] = {{0.f,0.f,0.f,0.f},{0.f,0.f,0.f,0.f},{0.f,0.f,0.f,0.f},{0.f,0.f,0.f,0.f}};
    _Float16* pbase = (_Float16*)(smem + 40960) + w * 1088;   // [16][68] f16, wave-private
    _Float16* pwr = pbase + lq * 68 + 4 * g;                  // + 16*t2
    const _Float16* prd = pbase + lq * 68 + 8 * g;            // + 32*ks
    const _Float16* frd = pbase + (l >> 4) * 68 + (l & 15) * 4;  // + i*272
    float* pF = p_out + (size_t)bh * (S_LEN * S_LEN)
              + (size_t)(q0 + 16 * w + (l >> 4)) * S_LEN + (l & 15) * 4;
    const int* mPc = mp + 4 * g;
    const float* bPc = bias2 + h * 4096 + 2047 - qq + 4 * g;
    const int kAoff = lq * 128;

    for (int t = 0; t < 32; ++t) {
        const int cb = (t & 1) * 16384;
        f32x4 bvm[4];
        #pragma unroll
        for (int t2 = 0; t2 < 4; ++t2) {
            const int4 mv = *(const int4*)(mPc + 16 * t2);
            const f32x4 bv = *(const f32x4*)(bPc + 16 * t2);
            bvm[t2][0] = (mv.x ? bv[0] : -1e9f) + lr2q;
            bvm[t2][1] = (mv.y ? bv[1] : -1e9f) + lr2q;
            bvm[t2][2] = (mv.z ? bv[2] : -1e9f) + lr2q;
            bvm[t2][3] = (mv.w ? bv[3] : -1e9f) + lr2q;
        }
        if (t < 31) {
            sKh += 4096; sVh += 64;
            char* nb = smem + ((t + 1) & 1) * 16384;
            gl_lds16(sKh, nb + tid * 16);
            gl_lds16(sKh + 2048, nb + 4096 + tid * 16);
            gl_lds16(sVh, nb + 8192 + tid * 16);
            gl_lds16(sVh + 65536, nb + 12288 + tid * 16);
        }
        __builtin_amdgcn_sched_barrier(0);
        #pragma unroll
        for (int t2 = 0; t2 < 4; ++t2) {
            const char* base = smem + cb + kAoff + t2 * 2048;
            f16x8 a0 = *(const f16x8*)(base + (g ^ r7) * 16);
            f16x8 a1 = *(const f16x8*)(base + ((4 + g) ^ r7) * 16);
            f32x4 acc = {0.f, 0.f, 0.f, 0.f};
            acc = __builtin_amdgcn_mfma_f32_16x16x32_f16(a0, qf[0], acc, 0, 0, 0);
            acc = __builtin_amdgcn_mfma_f32_16x16x32_f16(a1, qf[1], acc, 0, 0, 0);
            float p0 = exp2v(fmaf(acc[0], C2, bvm[t2][0]));
            float p1 = exp2v(fmaf(acc[1], C2, bvm[t2][1]));
            float p2 = exp2v(fmaf(acc[2], C2, bvm[t2][2]));
            float p3 = exp2v(fmaf(acc[3], C2, bvm[t2][3]));
            f16x4v ph;
            ph[0] = (_Float16)p0; ph[1] = (_Float16)p1;
            ph[2] = (_Float16)p2; ph[3] = (_Float16)p3;
            *(f16x4v*)(pwr + 16 * t2) = ph;
        }
        // wave-private p visibility: lgkm only, NO block barrier
        asm volatile("s_waitcnt lgkmcnt(0)" ::: "memory");
        __builtin_amdgcn_sched_barrier(0);
        // flush: 4 plain stores, each 4 rows x 256B contiguous
        #pragma unroll
        for (int i = 0; i < 4; ++i) {
            f16x4v v = *(const f16x4v*)(frd + i * 272);
            f32x4 wv;
            wv[0] = (float)v[0]; wv[1] = (float)v[1];
            wv[2] = (float)v[2]; wv[3] = (float)v[3];
            *(f32x4*)(pF + (size_t)(4 * i) * S_LEN) = wv;
        }
        // PV: A = P [16q x 64k] (own pbuf), B = V^T
        const f16x8 pf0 = *(const f16x8*)prd;
        const f16x8 pf1 = *(const f16x8*)(prd + 32);
        #pragma unroll
        for (int n = 0; n < 4; ++n) {
            const char* vb = smem + cb + 8192 + lq * 128 + n * 2048;
            f16x8 b0 = *(const f16x8*)(vb + (g ^ r7) * 16);
            f16x8 b1 = *(const f16x8*)(vb + ((4 + g) ^ r7) * 16);
            acco[n] = __builtin_amdgcn_mfma_f32_16x16x32_f16(pf0, b0, acco[n], 0, 0, 0);
            acco[n] = __builtin_amdgcn_mfma_f32_16x16x32_f16(pf1, b1, acco[n], 0, 0, 0);
        }
        mPc += 64; bPc += 64; pF += 64;
        // counted end-of-iter: loads+staging landed, 4 flush stores in flight
        asm volatile("s_waitcnt vmcnt(4)" ::: "memory");
        __builtin_amdgcn_sched_barrier(0);
        __builtin_amdgcn_s_barrier();
        __builtin_amdgcn_sched_barrier(0);
    }

    // ---- epilogue: direct per-wave stores (no cross-wave reduce) ----
    #pragma unroll
    for (int n = 0; n < 4; ++n) {
        #pragma unroll
        for (int r = 0; r < 4; ++r) {
            outp[((size_t)bh * S_LEN + q0 + 16 * w + 4 * g + r) * D_HEAD + 16 * n + lq]
                = acco[n][r];
        }
    }
}

extern "C" void kernel_launch(void* const* d_in, const int* in_sizes, int n_in,
                              void* d_out, int out_size, void* d_ws, size_t ws_size,
                              hipStream_t stream) {
    const float* Q = (const float*)d_in[0];
    const float* K = (const float*)d_in[1];
    const float* V = (const float*)d_in[2];
    const int* mask = (const int*)d_in[3];
    const float* table = (const float*)d_in[4];

    float* outp = (float*)d_out;
    float* p_out = outp + (size_t)4 * 4 * 2048 * 64;   // out first, then p_attn

    float* bias_d = (float*)d_ws;                                   // 64 KB
    _Float16* kh = (_Float16*)((char*)d_ws + 65536);                // 4 MB
    _Float16* vt = kh + (size_t)16 * S_LEN * D_HEAD;                // 4 MB

    prep_bias<<<16, 256, 0, stream>>>(table, bias_d);
    prep_half<<<1024, 256, 0, stream>>>(K, kh);
    prep_vt<<<dim3(32, 16), 256, 0, stream>>>(V, vt);
    attn_main<<<512, 256, 0, stream>>>(Q, mask, bias_d, kh, vt, outp, p_out);
}

// Round 12
// 98.448 us; speedup vs baseline: 1.1593x; 1.1593x over previous
//
#include <hip/hip_runtime.h>
#include <math.h>

typedef __attribute__((ext_vector_type(4))) float f32x4;
typedef _Float16 f16x8 __attribute__((ext_vector_type(8)));
typedef _Float16 f16x4v __attribute__((ext_vector_type(4)));

#define S_LEN 2048
#define D_HEAD 64
#define C2 0.18033688011112043f   /* log2(e)/8 */

static __device__ __forceinline__ float exp2v(float x) { // v_exp_f32 = 2^x
    float r; asm("v_exp_f32 %0, %1" : "=v"(r) : "v"(x)); return r;
}

static __device__ __forceinline__ void gl_lds16(const void* g, void* l) {
    __builtin_amdgcn_global_load_lds(
        (const __attribute__((address_space(1))) unsigned int*)g,
        (__attribute__((address_space(3))) unsigned int*)l, 16, 0, 0);
}

// ---- prep: T5 bias baked to [h][delta+2047], pre-scaled by log2(e)/8 ----
__global__ void prep_bias(const float* __restrict__ table, float* __restrict__ bias_d) {
    int idx = blockIdx.x * blockDim.x + threadIdx.x;   // 0..4095
    if (idx >= 4096) return;
    int delta = idx - 2047;                 // k - q
    int bpos = (delta > 0) ? 16 : 0;
    int ad = delta < 0 ? -delta : delta;
    int rel;
    if (ad < 8) {
        rel = bpos + ad;
    } else {
        float rp = (float)ad;
        int lg = 8 + (int)(logf(rp / 8.0f) / 2.772588722239781f * 8.0f);  // log(16)
        if (lg > 15) lg = 15;
        rel = bpos + lg;
    }
    #pragma unroll
    for (int h = 0; h < 4; ++h)
        bias_d[h * 4096 + idx] = C2 * table[rel * 4 + h];
}

// ---- prep: elementwise fp32 -> fp16 (for K) ----
__global__ void prep_half(const float* __restrict__ src, _Float16* __restrict__ dst) {
    size_t i8 = ((size_t)blockIdx.x * 256 + threadIdx.x) * 8;
    f32x4 a = *(const f32x4*)(src + i8);
    f32x4 b = *(const f32x4*)(src + i8 + 4);
    f16x8 h;
    h[0] = (_Float16)a[0]; h[1] = (_Float16)a[1];
    h[2] = (_Float16)a[2]; h[3] = (_Float16)a[3];
    h[4] = (_Float16)b[0]; h[5] = (_Float16)b[1];
    h[6] = (_Float16)b[2]; h[7] = (_Float16)b[3];
    *(f16x8*)(dst + i8) = h;
}

// ---- prep: V [bh][k][d] fp32  ->  V^T fp16 [bh][d][k] ----
__global__ void prep_vt(const float* __restrict__ V, _Float16* __restrict__ vt) {
    __shared__ float tile[64][65];
    const int bh = blockIdx.y;
    const int k0 = blockIdx.x * 64;
    const int t = threadIdx.x;
    {
        int r = t >> 2, c0 = (t & 3) * 16;
        const float* src = V + ((size_t)bh * S_LEN + k0 + r) * D_HEAD + c0;
        #pragma unroll
        for (int i = 0; i < 16; i += 4) {
            f32x4 v = *(const f32x4*)(src + i);
            tile[r][c0 + i + 0] = v[0];
            tile[r][c0 + i + 1] = v[1];
            tile[r][c0 + i + 2] = v[2];
            tile[r][c0 + i + 3] = v[3];
        }
    }
    __syncthreads();
    {
        int d = t >> 2, kc = (t & 3) * 16;
        size_t ob = ((size_t)bh * D_HEAD + d) * S_LEN + k0 + kc;
        #pragma unroll
        for (int half = 0; half < 2; ++half) {
            f16x8 hv;
            #pragma unroll
            for (int i = 0; i < 8; ++i)
                hv[i] = (_Float16)tile[kc + half * 8 + i][d];
            *(f16x8*)(vt + ob + half * 8) = hv;
        }
    }
}

// ============================================================================
// main: two-pass fused attention, log2-domain max-free softmax, all-fp16.
// Round-12: WAVE-ALTERNATING P2. 8 waves = 4 wq x 2 wk as r9, but per k-tile
// t only the wk==(t&1) waves compute (full 64 contiguous k for their 16 rows:
// 8 QK + 8 PV MFMA, p -> wave-private pbuf[16][72]); the other waves flush
// their PREVIOUS tile's p as 4 x 1KB store-instructions (4 rows x 256B runs)
// and register-prefetch the next tile's mask/bias. Occupancy (16 waves/CU),
// barrier count (1/iter), staging (dbuf + counted vmcnt) all == r9; only the
// store run-length changes 128B->256B. vmcnt: passive {stage2,flush4,mb8}->
// vmcnt(12) retires staging only; active {stage2}->vmcnt(0) retires its old
// stores (they rode ~1.5 periods).
// LDS 51712B: [0,32K) staging dbuf (P1 K128; P2 K64+V64); [32K,50K) pbuf
// 8 x 2304B; [50.0K,50.5K) stats. Q staged in [0,8K) pre-P1 (r9 pattern).
// ============================================================================
__launch_bounds__(512, 4)
__global__ void attn_main(const float* __restrict__ Q, const int* __restrict__ mask,
                          const float* __restrict__ bias2,
                          const _Float16* __restrict__ kh_g,
                          const _Float16* __restrict__ vt_g,
                          float* __restrict__ outp, float* __restrict__ p_out) {
    __shared__ __align__(16) char smem[51712];
    float* stats = (float*)(smem + 51200);    // 128 floats

    const int tid = threadIdx.x;
    const int w = tid >> 6, l = tid & 63;
    const int wq = w & 3, wk = w >> 2;
    const int g = l >> 4, lq = l & 15;
    const int r7 = lq & 7;
    const int bid = blockIdx.x;
    const int bh = bid & 15, b = bh >> 2, h = bh & 3;   // bid%8 == bh%8: bh pinned per XCD
    const int q0 = (bid >> 4) * 64;

    const float* Qp = Q + (size_t)bh * (S_LEN * D_HEAD);
    const int* mp = mask + b * S_LEN;
    const _Float16* khp = kh_g + (size_t)bh * (S_LEN * D_HEAD);
    const _Float16* vhp = vt_g + (size_t)bh * (S_LEN * D_HEAD);

    // ---- stage Q -> f16 (swizzled ds_write) at smem[0..8K) ----
    _Float16* qarea = (_Float16*)smem;
    {
        int sr = tid >> 3, tb = tid & 7;
        const float* src = Qp + (size_t)(q0 + sr) * D_HEAD + tb * 8;
        f32x4 a = *(const f32x4*)src;
        f32x4 c = *(const f32x4*)(src + 4);
        f16x8 hv;
        hv[0] = (_Float16)a[0]; hv[1] = (_Float16)a[1];
        hv[2] = (_Float16)a[2]; hv[3] = (_Float16)a[3];
        hv[4] = (_Float16)c[0]; hv[5] = (_Float16)c[1];
        hv[6] = (_Float16)c[2]; hv[7] = (_Float16)c[3];
        *(f16x8*)(qarea + sr * 64 + ((tb ^ (sr & 7)) * 8)) = hv;
    }
    __syncthreads();
    f16x8 qf[2];
    const int qrow = 16 * wq + lq;
    #pragma unroll
    for (int c = 0; c < 2; ++c)
        qf[c] = *(const f16x8*)(qarea + qrow * 64 + ((4 * c + g) ^ r7) * 8);
    __syncthreads();   // all Q reads done before staging overwrites [0..8K)

    const int qq = q0 + qrow;

    // hoisted staging geometry
    const int rr3 = tid >> 3;                       // chunk row 0..63
    const int ub0 = (((tid & 7) ^ (rr3 & 7)) * 8);  // swizzled 8-elem block
    // pass-1 prologue: stage K rows 0..127 -> smem[0..16K)
    const _Float16* s1a = khp + (size_t)rr3 * 64 + ub0;
    gl_lds16(s1a, smem + tid * 16);
    gl_lds16(s1a + 4096, smem + 8192 + tid * 16);
    __syncthreads();   // full drain, once

    // ================= PASS 1: l = sum(2^s2), K-tile 128, 16 iters =================
    const int* mP1 = mp + 64 * wk + 4 * g;
    const float* bP1 = bias2 + h * 4096 + 2047 - qq + 64 * wk + 4 * g;
    float lsum = 0.0f;
    for (int t = 0; t < 16; ++t) {
        const char* kb = smem + (t & 1) * 16384;
        int4 mv[4]; f32x4 bv[4];
        #pragma unroll
        for (int t2 = 0; t2 < 4; ++t2) {
            mv[t2] = *(const int4*)(mP1 + 16 * t2);
            bv[t2] = *(const f32x4*)(bP1 + 16 * t2);
        }
        if (t < 15) {
            s1a += 8192;
            char* nb = smem + ((t + 1) & 1) * 16384 + tid * 16;
            gl_lds16(s1a, nb);
            gl_lds16(s1a + 4096, nb + 8192);
        }
        __builtin_amdgcn_sched_barrier(0);
        #pragma unroll
        for (int t2 = 0; t2 < 4; ++t2) {
            const int krow = 64 * wk + 16 * t2 + lq;
            f32x4 acc = {0.f, 0.f, 0.f, 0.f};
            #pragma unroll
            for (int c = 0; c < 2; ++c) {
                f16x8 af = *(const f16x8*)(kb + krow * 128 + ((4 * c + g) ^ r7) * 16);
                acc = __builtin_amdgcn_mfma_f32_16x16x32_f16(af, qf[c], acc, 0, 0, 0);
            }
            float s0 = mv[t2].x ? fmaf(acc[0], C2, bv[t2][0]) : -1e9f;
            float s1 = mv[t2].y ? fmaf(acc[1], C2, bv[t2][1]) : -1e9f;
            float s2 = mv[t2].z ? fmaf(acc[2], C2, bv[t2][2]) : -1e9f;
            float s3 = mv[t2].w ? fmaf(acc[3], C2, bv[t2][3]) : -1e9f;
            lsum += exp2v(s0) + exp2v(s1) + exp2v(s2) + exp2v(s3);
        }
        mP1 += 128; bP1 += 128;
        asm volatile("s_waitcnt vmcnt(0)" ::: "memory");
        __builtin_amdgcn_sched_barrier(0);
        __builtin_amdgcn_s_barrier();
        __builtin_amdgcn_sched_barrier(0);
    }
    lsum += __shfl_xor(lsum, 16);
    lsum += __shfl_xor(lsum, 32);
    if (g == 0) stats[wk * 64 + qrow] = lsum;

    // ---- pass-2 staging pointers + prologue (buf0: K64, V64) ----
    const _Float16* sKh = khp + (size_t)rr3 * 64 + ub0;
    const _Float16* sVh = vhp + (size_t)rr3 * 2048 + ub0;
    gl_lds16(sKh, smem + tid * 16);
    gl_lds16(sVh, smem + 8192 + tid * 16);
    __syncthreads();   // stats visible + buf0 staged (full drain, once)
    float lr2q;
    {
        float L = stats[qrow] + stats[64 + qrow];
        float lg; asm("v_log_f32 %0, %1" : "=v"(lg) : "v"(L));
        lr2q = -lg;    // p = 2^(s2 + lr2q)
    }

    // ================= PASS 2: wave-alternating, 256B-run flush =================
    f32x4 acco[4] = {{0.f,0.f,0.f,0.f},{0.f,0.f,0.f,0.f},{0.f,0.f,0.f,0.f},{0.f,0.f,0.f,0.f}};
    _Float16* pbase = (_Float16*)(smem + 32768) + w * 1152;   // [16][72] f16, wave-private
    _Float16* pwr = pbase + lq * 72 + 4 * g;                  // + 16*t2
    const _Float16* prd = pbase + lq * 72 + 8 * g;            // pf0; +32 -> pf1
    const _Float16* frd = pbase + (l >> 4) * 72 + (l & 15) * 4;  // + i*288
    float* pF = p_out + (size_t)bh * (S_LEN * S_LEN)
              + (size_t)(q0 + 16 * wq + (l >> 4)) * S_LEN + (l & 15) * 4
              + 64 * wk;                                      // first flushed tile = wk
    const int* mPc = mp + 4 * g;
    const float* bPc = bias2 + h * 4096 + 2047 - qq + 4 * g;

    // mask/bias prefetch for this wave's FIRST active tile (tile wk)
    f32x4 bvmr[4];
    #pragma unroll
    for (int t2 = 0; t2 < 4; ++t2) {
        const int4 mv = *(const int4*)(mPc + 64 * wk + 16 * t2);
        const f32x4 bv = *(const f32x4*)(bPc + 64 * wk + 16 * t2);
        bvmr[t2][0] = (mv.x ? bv[0] : -1e9f) + lr2q;
        bvmr[t2][1] = (mv.y ? bv[1] : -1e9f) + lr2q;
        bvmr[t2][2] = (mv.z ? bv[2] : -1e9f) + lr2q;
        bvmr[t2][3] = (mv.w ? bv[3] : -1e9f) + lr2q;
    }

    for (int t = 0; t < 32; ++t) {
        const int cb = (t & 1) * 16384;
        const bool active = (wk == (t & 1));
        if (t < 31) {   // cooperative staging of tile t+1 (all waves)
            sKh += 4096; sVh += 64;
            char* d0 = smem + ((t + 1) & 1) * 16384 + tid * 16;
            gl_lds16(sKh, d0);
            gl_lds16(sVh, d0 + 8192);
        }
        if (active) {
            // compute tile t: 16 rows x full 64 k
            __builtin_amdgcn_sched_barrier(0);
            #pragma unroll
            for (int t2 = 0; t2 < 4; ++t2) {
                const char* kbase = smem + cb + (16 * t2 + lq) * 128;
                f16x8 a0 = *(const f16x8*)(kbase + (g ^ r7) * 16);
                f16x8 a1 = *(const f16x8*)(kbase + ((4 + g) ^ r7) * 16);
                f32x4 acc = {0.f, 0.f, 0.f, 0.f};
                acc = __builtin_amdgcn_mfma_f32_16x16x32_f16(a0, qf[0], acc, 0, 0, 0);
                acc = __builtin_amdgcn_mfma_f32_16x16x32_f16(a1, qf[1], acc, 0, 0, 0);
                float p0 = exp2v(fmaf(acc[0], C2, bvmr[t2][0]));
                float p1 = exp2v(fmaf(acc[1], C2, bvmr[t2][1]));
                float p2 = exp2v(fmaf(acc[2], C2, bvmr[t2][2]));
                float p3 = exp2v(fmaf(acc[3], C2, bvmr[t2][3]));
                f16x4v ph;
                ph[0] = (_Float16)p0; ph[1] = (_Float16)p1;
                ph[2] = (_Float16)p2; ph[3] = (_Float16)p3;
                *(f16x4v*)(pwr + 16 * t2) = ph;
            }
            const f16x8 pf0 = *(const f16x8*)prd;
            const f16x8 pf1 = *(const f16x8*)(prd + 32);
            #pragma unroll
            for (int n = 0; n < 4; ++n) {
                const char* vb = smem + cb + 8192 + (16 * n + lq) * 128;
                f16x8 b0 = *(const f16x8*)(vb + (g ^ r7) * 16);
                f16x8 b1 = *(const f16x8*)(vb + ((4 + g) ^ r7) * 16);
                acco[n] = __builtin_amdgcn_mfma_f32_16x16x32_f16(pf0, b0, acco[n], 0, 0, 0);
                acco[n] = __builtin_amdgcn_mfma_f32_16x16x32_f16(pf1, b1, acco[n], 0, 0, 0);
            }
            // staging + (old flush stores, ~1.5 periods old) must retire
            asm volatile("s_waitcnt vmcnt(0)" ::: "memory");
        } else {
            // flush previous tile's p: 4 stores x (4 rows x 256B runs)
            if (t > 0) {
                #pragma unroll
                for (int i = 0; i < 4; ++i) {
                    f16x4v v = *(const f16x4v*)(frd + i * 288);
                    f32x4 wv;
                    wv[0] = (float)v[0]; wv[1] = (float)v[1];
                    wv[2] = (float)v[2]; wv[3] = (float)v[3];
                    *(f32x4*)(pF + (size_t)(4 * i) * S_LEN) = wv;
                }
                pF += 128;
            }
            // prefetch mask/bias for next tile (this wave's next active = t+1)
            if (t < 31) {
                #pragma unroll
                for (int t2 = 0; t2 < 4; ++t2) {
                    const int4 mv = *(const int4*)(mPc + 64 * (t + 1) + 16 * t2);
                    const f32x4 bv = *(const f32x4*)(bPc + 64 * (t + 1) + 16 * t2);
                    bvmr[t2][0] = (mv.x ? bv[0] : -1e9f) + lr2q;
                    bvmr[t2][1] = (mv.y ? bv[1] : -1e9f) + lr2q;
                    bvmr[t2][2] = (mv.z ? bv[2] : -1e9f) + lr2q;
                    bvmr[t2][3] = (mv.w ? bv[3] : -1e9f) + lr2q;
                }
            }
            // retire staging (oldest); flush stores + mb loads stay in flight
            if (t == 0) { asm volatile("s_waitcnt vmcnt(8)" ::: "memory"); }
            else        { asm volatile("s_waitcnt vmcnt(12)" ::: "memory"); }
        }
        __builtin_amdgcn_sched_barrier(0);
        __builtin_amdgcn_s_barrier();
        __builtin_amdgcn_sched_barrier(0);
    }
    // final flush: wk==1 waves' last active tile (31)
    if (wk == 1) {
        #pragma unroll
        for (int i = 0; i < 4; ++i) {
            f16x4v v = *(const f16x4v*)(frd + i * 288);
            f32x4 wv;
            wv[0] = (float)v[0]; wv[1] = (float)v[1];
            wv[2] = (float)v[2]; wv[3] = (float)v[3];
            *(f32x4*)(pF + (size_t)(4 * i) * S_LEN) = wv;
        }
    }

    // ---- reduce the two wk halves (stage area is dead) and store out ----
    float* ored = (float*)smem;    // [64 q][64 d]
    __syncthreads();
    if (wk == 1) {
        #pragma unroll
        for (int n = 0; n < 4; ++n)
            #pragma unroll
            for (int r = 0; r < 4; ++r)
                ored[(wq * 16 + 4 * g + r) * 64 + 16 * n + lq] = acco[n][r];
    }
    __syncthreads();
    if (wk == 0) {
        #pragma unroll
        for (int n = 0; n < 4; ++n) {
            #pragma unroll
            for (int r = 0; r < 4; ++r) {
                float v = acco[n][r] + ored[(wq * 16 + 4 * g + r) * 64 + 16 * n + lq];
                outp[((size_t)bh * S_LEN + q0 + 16 * wq + 4 * g + r) * D_HEAD + 16 * n + lq] = v;
            }
        }
    }
}

extern "C" void kernel_launch(void* const* d_in, const int* in_sizes, int n_in,
                              void* d_out, int out_size, void* d_ws, size_t ws_size,
                              hipStream_t stream) {
    const float* Q = (const float*)d_in[0];
    const float* K = (const float*)d_in[1];
    const float* V = (const float*)d_in[2];
    const int* mask = (const int*)d_in[3];
    const float* table = (const float*)d_in[4];

    float* outp = (float*)d_out;
    float* p_out = outp + (size_t)4 * 4 * 2048 * 64;   // out first, then p_attn

    float* bias_d = (float*)d_ws;                                   // 64 KB
    _Float16* kh = (_Float16*)((char*)d_ws + 65536);                // 4 MB
    _Float16* vt = kh + (size_t)16 * S_LEN * D_HEAD;                // 4 MB

    prep_bias<<<16, 256, 0, stream>>>(table, bias_d);
    prep_half<<<1024, 256, 0, stream>>>(K, kh);
    prep_vt<<<dim3(32, 16), 256, 0, stream>>>(V, vt);
    attn_main<<<512, 512, 0, stream>>>(Q, mask, bias_d, kh, vt, outp, p_out);
}